// Round 6
// baseline (268.804 us; speedup 1.0000x reference)
//
#include <hip/hip_runtime.h>
#include <hip/hip_bf16.h>
#include <math.h>

#define WAVE 64

// ---------------- K1: per-token softmax + top1/top2 ----------------
// One 64-lane wave per token; lane e holds logit[s][e]. Packs the result
// as int4{t1, t2, bits(w1), bits(w2)} -> one 16B store per token.
__global__ void __launch_bounds__(256)
router_softmax_top2(const float* __restrict__ x,
                    int4* __restrict__ tok,
                    int S) {
    const int wavesPerBlock = blockDim.x >> 6;
    const int wid  = threadIdx.x >> 6;
    const int lane = threadIdx.x & 63;
    const int s = blockIdx.x * wavesPerBlock + wid;
    if (s >= S) return;

    float v = x[(size_t)s * 64 + lane];

    // argmax with lowest-index tiebreak (matches jnp.argmax)
    float bv = v; int bi = lane;
    #pragma unroll
    for (int off = 32; off >= 1; off >>= 1) {
        float ov = __shfl_xor(bv, off, WAVE);
        int   oi = __shfl_xor(bi, off, WAVE);
        if (ov > bv || (ov == bv && oi < bi)) { bv = ov; bi = oi; }
    }
    const float m = bv;
    const int t1 = bi;

    // fp32 softmax
    float e = expf(v - m);
    float sum = e;
    #pragma unroll
    for (int off = 32; off >= 1; off >>= 1) sum += __shfl_xor(sum, off, WAVE);
    const float p = e / sum;

    // second argmax with top1 masked out
    float v2 = (lane == t1) ? -INFINITY : v;
    float bv2 = v2; int bi2 = lane;
    #pragma unroll
    for (int off = 32; off >= 1; off >>= 1) {
        float ov = __shfl_xor(bv2, off, WAVE);
        int   oi = __shfl_xor(bi2, off, WAVE);
        if (ov > bv2 || (ov == bv2 && oi < bi2)) { bv2 = ov; bi2 = oi; }
    }
    const int t2 = bi2;

    const float p1 = __shfl(p, t1, WAVE);
    const float p2 = __shfl(p, t2, WAVE);

    if (lane == 0) {
        tok[s] = make_int4(t1, t2, __float_as_int(p1), __float_as_int(p2));
    }
}

// ---------------- K2: per-expert ballot ranks (in-place pos update) -------
// 64 waves total, wave = expert e. cumsum-rank via ballot+popcount.
// Sweep A: top-1 -> overwrite tok[s].x with flat row position e*CAP+r
// (or -1 if dropped); also yields total1 = full top-1 count of e.
// Sweep B: top-2 with +total1 offset -> overwrite tok[s].y.
// Every token's .x is written by exactly one wave (its top-1 expert's),
// same for .y -> deterministic, race-free 4B field updates.
__global__ void __launch_bounds__(256)
rank_pos(int4* __restrict__ tok,
         int nchunks, int CAP) {
    const int e    = (blockIdx.x * blockDim.x + threadIdx.x) >> 6; // expert id
    const int lane = threadIdx.x & 63;
    const unsigned long long lt = (1ull << lane) - 1ull;
    int* ti = (int*)tok;   // int view: token s fields at 4*s + {0,1,2,3}

    int run1 = 0;
    #pragma unroll 4
    for (int c = 0; c < nchunks; ++c) {
        const int s = c * 64 + lane;
        const int t1 = ti[4 * s + 0];
        const unsigned long long m1 = __ballot(t1 == e);
        if (t1 == e) {
            const int r = run1 + __popcll(m1 & lt);
            ti[4 * s + 0] = (r < CAP) ? (e * CAP + r) : -1;
        }
        run1 += __popcll(m1);
    }

    int run2 = 0;
    #pragma unroll 4
    for (int c = 0; c < nchunks; ++c) {
        const int s = c * 64 + lane;
        const int t2 = ti[4 * s + 1];
        const unsigned long long m2 = __ballot(t2 == e);
        if (t2 == e) {
            const int r = run2 + __popcll(m2 & lt) + run1;  // + total1[e]
            ti[4 * s + 1] = (r < CAP) ? (e * CAP + r) : -1;
        }
        run2 += __popcll(m2);
    }
}

// ---------------- K3: pure-store fill + post-barrier patch ----------------
// One block per token. Inner loop is NOTHING BUT float4 zero stores (matches
// runtime-fill BW; R2's per-element selects were the BW killer). The
// __syncthreads() drains vmcnt (WAW ordering), then threads 0/1 patch the
// <=2 nonzero slots while the lines are still L2-resident.
__global__ void __launch_bounds__(256)
fill_patch(const int4* __restrict__ tok,
           float* __restrict__ out,
           int ROW, size_t secoff) {
    const int s = blockIdx.x;
    float* crow_f = out + (size_t)s * ROW;
    float* mrow_f = out + secoff + (size_t)s * ROW;
    float4* crow = (float4*)crow_f;
    float4* mrow = (float4*)mrow_f;
    const float4 z = make_float4(0.0f, 0.0f, 0.0f, 0.0f);

    #pragma unroll
    for (int i = 0; i < 16; ++i) {
        crow[threadIdx.x + i * 256] = z;
        mrow[threadIdx.x + i * 256] = z;
    }

    __syncthreads();   // implicit s_waitcnt vmcnt(0): zeros committed

    if (threadIdx.x < 2) {
        const int4 t = tok[s];
        const int   p = (threadIdx.x == 0) ? t.x : t.y;
        const float v = __int_as_float((threadIdx.x == 0) ? t.z : t.w);
        if (p >= 0) {
            crow_f[p] = v;
            mrow_f[p] = 1.0f;
        }
    }
}

extern "C" void kernel_launch(void* const* d_in, const int* in_sizes, int n_in,
                              void* d_out, int out_size, void* d_ws, size_t ws_size,
                              hipStream_t stream) {
    const float* x = (const float*)d_in[0];
    float* out = (float*)d_out;

    const int E = 64;
    const int S = in_sizes[0] / E;            // 8192
    int cap = (int)(2.0 * S / E);
    cap += cap % 2;
    if (cap < 4) cap = 4;                     // 256

    const int nchunks = S / 64;               // 128
    const int ROW = E * cap;                  // 16384 floats per row
    const size_t secoff = (size_t)S * ROW;

    int4* tok = (int4*)d_ws;                  // S * 16 bytes

    // 1) softmax + top2 (one wave per token) -> tok{t1,t2,w1,w2}
    {
        const int wavesPerBlock = 4;
        const int blocks = (S + wavesPerBlock - 1) / wavesPerBlock;
        router_softmax_top2<<<blocks, wavesPerBlock * 64, 0, stream>>>(x, tok, S);
    }

    // 2) ballot ranks, in-place: tok{pos1,pos2,w1,w2}
    rank_pos<<<16, 256, 0, stream>>>(tok, nchunks, cap);

    // 3) single pass over the 1.074 GB output: pure-store fill + patch
    fill_patch<<<S, 256, 0, stream>>>(tok, out, ROW, secoff);
}

// Round 7
// 222.935 us; speedup vs baseline: 1.2058x; 1.2058x over previous
//
#include <hip/hip_runtime.h>
#include <hip/hip_bf16.h>
#include <math.h>

#define WAVE 64

// ============================================================================
// A/A VARIANCE PROBE: this is Round-1's kernel, resubmitted VERBATIM.
// Six structural variants measured 224..269 us with contradictory
// attributions; this re-measure of the best (224) determines whether that
// delta was structure or run-to-run noise before any further optimization.
// ============================================================================

// ---------------- Kernel A: per-token softmax + top1/top2 ----------------
// One 64-lane wave per token (row of 64 logits). Lane e holds logit[s][e].
__global__ void router_softmax_top2(const float* __restrict__ x,
                                    int* __restrict__ top1,
                                    int* __restrict__ top2,
                                    float* __restrict__ w1,
                                    float* __restrict__ w2,
                                    int S) {
    const int wavesPerBlock = blockDim.x >> 6;
    const int wid  = threadIdx.x >> 6;
    const int lane = threadIdx.x & 63;
    const int s = blockIdx.x * wavesPerBlock + wid;
    if (s >= S) return;

    float v = x[(size_t)s * 64 + lane];

    // argmax with lowest-index tiebreak (matches jnp.argmax)
    float bv = v; int bi = lane;
    #pragma unroll
    for (int off = 32; off >= 1; off >>= 1) {
        float ov = __shfl_xor(bv, off, WAVE);
        int   oi = __shfl_xor(bi, off, WAVE);
        if (ov > bv || (ov == bv && oi < bi)) { bv = ov; bi = oi; }
    }
    const float m = bv;
    const int t1 = bi;

    // fp32 softmax
    float e = expf(v - m);
    float sum = e;
    #pragma unroll
    for (int off = 32; off >= 1; off >>= 1) sum += __shfl_xor(sum, off, WAVE);
    const float p = e / sum;

    // second argmax with top1 masked out
    float v2 = (lane == t1) ? -INFINITY : v;
    float bv2 = v2; int bi2 = lane;
    #pragma unroll
    for (int off = 32; off >= 1; off >>= 1) {
        float ov = __shfl_xor(bv2, off, WAVE);
        int   oi = __shfl_xor(bi2, off, WAVE);
        if (ov > bv2 || (ov == bv2 && oi < bi2)) { bv2 = ov; bi2 = oi; }
    }
    const int t2 = bi2;

    const float p1 = __shfl(p, t1, WAVE);
    const float p2 = __shfl(p, t2, WAVE);

    if (lane == 0) {
        top1[s] = t1; top2[s] = t2;
        w1[s] = p1;   w2[s] = p2;
    }
}

// ---------------- Kernel B1: per-chunk expert histograms ----------------
// One 64-lane block per 64-token chunk. Lane e counts tokens routed to expert e.
__global__ void chunk_hist(const int* __restrict__ top1,
                           const int* __restrict__ top2,
                           int* __restrict__ hist1,
                           int* __restrict__ hist2) {
    const int c = blockIdx.x;
    const int lane = threadIdx.x;
    const int t1 = top1[c * 64 + lane];
    const int t2 = top2[c * 64 + lane];
    int c1 = 0, c2 = 0;
    #pragma unroll 8
    for (int j = 0; j < 64; ++j) {
        c1 += (__shfl(t1, j, WAVE) == lane);
        c2 += (__shfl(t2, j, WAVE) == lane);
    }
    hist1[c * 64 + lane] = c1;
    hist2[c * 64 + lane] = c2;
}

// ---------------- Kernel B2: exclusive scan over chunks, per expert ----------------
// One 64-thread block; thread e scans its expert across all chunks.
__global__ void scan_hist(const int* __restrict__ hist1,
                          const int* __restrict__ hist2,
                          int* __restrict__ base1,
                          int* __restrict__ base2,
                          int* __restrict__ total1,
                          int nchunks) {
    const int e = threadIdx.x;
    int r1 = 0, r2 = 0;
    for (int c = 0; c < nchunks; ++c) {
        base1[c * 64 + e] = r1; r1 += hist1[c * 64 + e];
        base2[c * 64 + e] = r2; r2 += hist2[c * 64 + e];
    }
    total1[e] = r1;  // sum(mask1, axis=0): offset for rank2
}

// ---------------- Kernel B3: final ranks + scatter ----------------
// One 64-lane block per chunk. Within-chunk stable rank via shfl loop,
// then scatter combine weight + sec mask.
__global__ void rank_scatter(const int* __restrict__ top1,
                             const int* __restrict__ top2,
                             const float* __restrict__ w1,
                             const float* __restrict__ w2,
                             const int* __restrict__ base1,
                             const int* __restrict__ base2,
                             const int* __restrict__ total1,
                             float* __restrict__ out,
                             int S, int CAP) {
    const int c = blockIdx.x;
    const int i = threadIdx.x;
    const int s = c * 64 + i;
    const int t1 = top1[s];
    const int t2 = top2[s];

    int cnt1 = 0, cnt2 = 0;
    #pragma unroll 8
    for (int j = 0; j < 64; ++j) {
        const int o1 = __shfl(t1, j, WAVE);
        const int o2 = __shfl(t2, j, WAVE);
        cnt1 += (o1 == t1) && (j < i);
        cnt2 += (o2 == t2) && (j < i);
    }

    const int rank1 = base1[c * 64 + t1] + cnt1;
    const int rank2 = base2[c * 64 + t2] + cnt2 + total1[t2];

    const size_t secoff = (size_t)S * 64 * CAP;
    if (rank1 < CAP) {
        const size_t idx = ((size_t)s * 64 + t1) * CAP + rank1;
        out[idx] = w1[s];
        out[secoff + idx] = 1.0f;
    }
    if (rank2 < CAP) {
        const size_t idx = ((size_t)s * 64 + t2) * CAP + rank2;
        out[idx] = w2[s];
        out[secoff + idx] = 1.0f;
    }
}

extern "C" void kernel_launch(void* const* d_in, const int* in_sizes, int n_in,
                              void* d_out, int out_size, void* d_ws, size_t ws_size,
                              hipStream_t stream) {
    const float* x = (const float*)d_in[0];
    float* out = (float*)d_out;

    const int E = 64;
    const int S = in_sizes[0] / E;            // 8192
    // capacity: floor(2.0*S/E), round up to even, min 4
    int cap = (int)(2.0 * S / E);
    cap += cap % 2;
    if (cap < 4) cap = 4;

    const int nchunks = S / 64;               // 128

    // workspace layout (all 4-byte elements)
    char* w = (char*)d_ws;
    int*   top1   = (int*)w;                      w += (size_t)S * 4;
    int*   top2   = (int*)w;                      w += (size_t)S * 4;
    float* w1     = (float*)w;                    w += (size_t)S * 4;
    float* w2     = (float*)w;                    w += (size_t)S * 4;
    int*   hist1  = (int*)w;                      w += (size_t)nchunks * 64 * 4;
    int*   hist2  = (int*)w;                      w += (size_t)nchunks * 64 * 4;
    int*   base1  = (int*)w;                      w += (size_t)nchunks * 64 * 4;
    int*   base2  = (int*)w;                      w += (size_t)nchunks * 64 * 4;
    int*   total1 = (int*)w;                      w += 64 * 4;

    // 1) zero the (mostly-sparse) dense output: this is the roofline cost
    hipMemsetAsync(d_out, 0, (size_t)out_size * sizeof(float), stream);

    // 2) softmax + top2 (4 waves per 256-thread block)
    {
        const int wavesPerBlock = 4;
        const int blocks = (S + wavesPerBlock - 1) / wavesPerBlock;
        router_softmax_top2<<<blocks, wavesPerBlock * 64, 0, stream>>>(
            x, top1, top2, w1, w2, S);
    }

    // 3) per-chunk histograms
    chunk_hist<<<nchunks, 64, 0, stream>>>(top1, top2, hist1, hist2);

    // 4) exclusive scan across chunks
    scan_hist<<<1, 64, 0, stream>>>(hist1, hist2, base1, base2, total1, nchunks);

    // 5) ranks + scatter
    rank_scatter<<<nchunks, 64, 0, stream>>>(top1, top2, w1, w2,
                                             base1, base2, total1,
                                             out, S, cap);
}